// Round 1
// baseline (258.113 us; speedup 1.0000x reference)
//
#include <hip/hip_runtime.h>
#include <hip/hip_bf16.h>

#define NCLS 5532
#define FDIM 256

// ---- 1. histogram of labels ----
__global__ void k_count(const int* __restrict__ labels, int n, int* __restrict__ counts) {
    int i = blockIdx.x * blockDim.x + threadIdx.x;
    int st = gridDim.x * blockDim.x;
    for (; i < n; i += st) {
        int l = labels[i];
        if (l >= 0 && l < NCLS) atomicAdd(&counts[l], 1);
    }
}

// ---- 2. exclusive scan of counts -> offsets, and of present -> rank ----
__global__ __launch_bounds__(256) void k_scan(const int* __restrict__ counts,
                                              int* __restrict__ offsets,
                                              int* __restrict__ rank) {
    const int T = 256;
    const int CH = (NCLS + T - 1) / T;  // 22
    __shared__ int s_c[T], s_p[T];
    int t = threadIdx.x;
    int base = t * CH;
    int cs = 0, ps = 0;
    for (int j = 0; j < CH; ++j) {
        int i = base + j;
        if (i < NCLS) { int c = counts[i]; cs += c; ps += (c > 0); }
    }
    s_c[t] = cs; s_p[t] = ps;
    __syncthreads();
    for (int off = 1; off < T; off <<= 1) {
        int vc = (t >= off) ? s_c[t - off] : 0;
        int vp = (t >= off) ? s_p[t - off] : 0;
        __syncthreads();
        s_c[t] += vc; s_p[t] += vp;
        __syncthreads();
    }
    int ec = (t == 0) ? 0 : s_c[t - 1];
    int ep = (t == 0) ? 0 : s_p[t - 1];
    for (int j = 0; j < CH; ++j) {
        int i = base + j;
        if (i < NCLS) {
            offsets[i] = ec; rank[i] = ep;
            int c = counts[i];
            ec += c; ep += (c > 0);
        }
    }
}

// ---- 3. build per-class row lists ----
__global__ void k_scatter(const int* __restrict__ labels, int n,
                          const int* __restrict__ offsets,
                          int* __restrict__ cursor,
                          int* __restrict__ rowlist) {
    int i = blockIdx.x * blockDim.x + threadIdx.x;
    int st = gridDim.x * blockDim.x;
    for (; i < n; i += st) {
        int l = labels[i];
        if (l >= 0 && l < NCLS) {
            int j = atomicAdd(&cursor[l], 1);
            rowlist[offsets[l] + j] = i;
        }
    }
}

// ---- 4. per-class mean + circular-queue write ----
__global__ __launch_bounds__(256) void k_means(const float* __restrict__ feats,
                                               const int* __restrict__ counts,
                                               const int* __restrict__ offsets,
                                               const int* __restrict__ rank,
                                               const int* __restrict__ rowlist,
                                               const int* __restrict__ tailp,
                                               float* __restrict__ outq,
                                               float* __restrict__ outl,
                                               int Q) {
    int c = blockIdx.x;
    int cnt = counts[c];
    if (cnt == 0) return;
    int t = threadIdx.x;
    int lane = t & 63;   // float4 column chunk
    int w = t >> 6;      // wave id: rows round-robin
    int off = offsets[c];
    float4 acc = make_float4(0.f, 0.f, 0.f, 0.f);
    for (int i = w; i < cnt; i += 4) {
        int r = rowlist[off + i];
        const float4 v = ((const float4*)(feats + (size_t)r * FDIM))[lane];
        acc.x += v.x; acc.y += v.y; acc.z += v.z; acc.w += v.w;
    }
    __shared__ float4 s_acc[3][64];
    if (w > 0) s_acc[w - 1][lane] = acc;
    __syncthreads();
    if (w == 0) {
        for (int k = 0; k < 3; ++k) {
            float4 v = s_acc[k][lane];
            acc.x += v.x; acc.y += v.y; acc.z += v.z; acc.w += v.w;
        }
        float inv = 1.0f / (float)cnt;
        int pos = (tailp[0] + rank[c]) % Q;
        if (pos < 0) pos += Q;
        float4 m = make_float4(acc.x * inv, acc.y * inv, acc.z * inv, acc.w * inv);
        ((float4*)(outq + (size_t)pos * FDIM))[lane] = m;
        if (lane == 0) outl[pos] = (float)c;
    }
}

extern "C" void kernel_launch(void* const* d_in, const int* in_sizes, int n_in,
                              void* d_out, int out_size, void* d_ws, size_t ws_size,
                              hipStream_t stream) {
    const float* feats  = (const float*)d_in[0];
    const int*   labels = (const int*)d_in[1];
    const float* queue  = (const float*)d_in[2];
    const float* qlabel = (const float*)d_in[3];
    const int*   tailp  = (const int*)d_in[4];
    int N  = in_sizes[1];
    int QF = in_sizes[2];
    int Q  = in_sizes[3];
    float* outq = (float*)d_out;
    float* outl = outq + (size_t)QF;

    int* counts  = (int*)d_ws;
    int* cursor  = counts + NCLS;
    int* offsets = cursor + NCLS;
    int* rank    = offsets + NCLS;
    int* rowlist = rank + NCLS;

    hipMemsetAsync(counts, 0, 2 * NCLS * sizeof(int), stream);
    // passthrough: unwritten queue slots must equal the old queue
    hipMemcpyAsync(outq, queue, (size_t)QF * sizeof(float), hipMemcpyDeviceToDevice, stream);
    hipMemcpyAsync(outl, qlabel, (size_t)Q * sizeof(float), hipMemcpyDeviceToDevice, stream);

    k_count<<<512, 256, 0, stream>>>(labels, N, counts);
    k_scan<<<1, 256, 0, stream>>>(counts, offsets, rank);
    k_scatter<<<512, 256, 0, stream>>>(labels, N, offsets, cursor, rowlist);
    k_means<<<NCLS, 256, 0, stream>>>(feats, counts, offsets, rank, rowlist, tailp, outq, outl, Q);
}